// Round 7
// baseline (329.628 us; speedup 1.0000x reference)
//
#include <hip/hip_runtime.h>

// ---------------------------------------------------------------------------
// GCN: out = spmm(A, relu(spmm(A, x)@w1 + b1)) @ w2 + b2
// Reordered: y1 = x@w1 ; h1 = relu(spmm(y1)+b1) ; y2 = h1@w2 ; out = spmm(y2)+b2
// R7: 2 rows per wave in both spmm kernels (dual independent gather streams,
//     16 outstanding loads/wave) to compensate low occupancy in the fused
//     spmm1+gemm2 kernel and cut spmm64 latency exposure. 7 dispatches.
// ---------------------------------------------------------------------------

typedef __bf16 v8bf __attribute__((ext_vector_type(8)));
typedef float  v4f  __attribute__((ext_vector_type(4)));

#define MAXB 800  // max buckets (N<=102400)

__device__ __forceinline__ unsigned short f2bf(float f) {
    unsigned u = __float_as_uint(f);
    unsigned r = u + 0x7fffu + ((u >> 16) & 1u);   // RNE
    return (unsigned short)(r >> 16);
}

// ---- hist + prep: bucket histogram, weight casts, sentinels ---------------
__global__ __launch_bounds__(256) void hist_prep(const int* __restrict__ arow,
                                                 int* __restrict__ counts, int E, int B,
                                                 const float* __restrict__ w1,
                                                 const float* __restrict__ w2,
                                                 unsigned short* __restrict__ w1T,
                                                 unsigned short* __restrict__ w2T,
                                                 int* __restrict__ rowptr,
                                                 int2* __restrict__ epkS, int N) {
    const int tid = threadIdx.x;
    int gi = blockIdx.x * 256 + tid;
    if (gi < 16384) {                       // w1T[n*128+k] = w1[k*128+n]
        int n = gi >> 7, k = gi & 127;
        w1T[gi] = f2bf(w1[k * 128 + n]);
    } else if (gi < 24576) {                // w2T[n*128+k] = w2[k*64+n]
        int i2 = gi - 16384;
        int n = i2 >> 7, k = i2 & 127;
        w2T[i2] = f2bf(w2[k * 64 + n]);
    } else if (gi < 24576 + 32) {           // sentinels for spmm overread
        epkS[E + (gi - 24576)] = make_int2(0, 0);
    } else if (gi == 24576 + 32) {
        rowptr[N] = E;
    }
    __shared__ int lh[MAXB];
    for (int i = tid; i < B; i += 256) lh[i] = 0;
    __syncthreads();
    const int base = blockIdx.x * 4096;
#pragma unroll
    for (int j = 0; j < 16; ++j) {
        int i = base + j * 256 + tid;
        if (i < E) atomicAdd(&lh[arow[i] >> 7], 1);
    }
    __syncthreads();
    for (int i = tid; i < B; i += 256) {
        int c = lh[i];
        if (c) atomicAdd(&counts[i], c);
    }
}

// ---- single-block exclusive scan over bucket counts -----------------------
__global__ __launch_bounds__(256) void scan_s(const int* __restrict__ counts,
                                              int* __restrict__ boff,
                                              int* __restrict__ gcursor, int B, int E) {
    __shared__ int lds[256];
    const int t = threadIdx.x;
    const int b0 = t * 4;
    int v[4];
    int s = 0;
#pragma unroll
    for (int j = 0; j < 4; ++j) {
        v[j] = (b0 + j < B) ? counts[b0 + j] : 0;
        s += v[j];
    }
    lds[t] = s;
    __syncthreads();
    for (int off = 1; off < 256; off <<= 1) {
        int tmp = 0;
        if (t >= off) tmp = lds[t - off];
        __syncthreads();
        if (t >= off) lds[t] += tmp;
        __syncthreads();
    }
    int run = (t > 0) ? lds[t - 1] : 0;
#pragma unroll
    for (int j = 0; j < 4; ++j) {
        if (b0 + j < B) {
            boff[b0 + j] = run;
            gcursor[b0 + j] = run;
        }
        run += v[j];
    }
    if (t == 255) boff[B] = E;
}

// ---- pass 1: bucket-order edges with LDS staging (coalesced out) ----------
__global__ __launch_bounds__(256) void partition_k(const int* __restrict__ arow,
                                                   const int* __restrict__ acol,
                                                   const float* __restrict__ aval,
                                                   int* __restrict__ gcursor,
                                                   int2* __restrict__ epk, int E, int B) {
    __shared__ int2 ldata[4096];
    __shared__ int ldest[4096];
    __shared__ int lhist[MAXB];
    __shared__ int lscan[MAXB];
    __shared__ int ldelta[MAXB];
    __shared__ int lcur[MAXB];
    __shared__ int stmp[256];
    const int tid = threadIdx.x;
    const int base = blockIdx.x * 4096;
    const int cnt = min(4096, E - base);

    for (int i = tid; i < MAXB; i += 256) {
        lhist[i] = 0;
        lcur[i] = 0;
    }
    __syncthreads();

    int rr[16];
#pragma unroll
    for (int j = 0; j < 16; ++j) {
        int i = base + j * 256 + tid;
        rr[j] = (i < E) ? arow[i] : -1;
        if (rr[j] >= 0) atomicAdd(&lhist[rr[j] >> 7], 1);
    }
    __syncthreads();

    const int b0 = tid * 4;
    int v[4];
    int s = 0;
#pragma unroll
    for (int j = 0; j < 4; ++j) {
        v[j] = (b0 + j < MAXB) ? lhist[b0 + j] : 0;
        s += v[j];
    }
    stmp[tid] = s;
    __syncthreads();
    for (int off = 1; off < 256; off <<= 1) {
        int tmp = 0;
        if (tid >= off) tmp = stmp[tid - off];
        __syncthreads();
        if (tid >= off) stmp[tid] += tmp;
        __syncthreads();
    }
    int run = (tid > 0) ? stmp[tid - 1] : 0;
#pragma unroll
    for (int j = 0; j < 4; ++j) {
        if (b0 + j < MAXB) lscan[b0 + j] = run;
        run += v[j];
    }
    __syncthreads();

    for (int b = tid; b < B; b += 256) {
        int c = lhist[b];
        if (c) ldelta[b] = atomicAdd(&gcursor[b], c) - lscan[b];
    }
    __syncthreads();

#pragma unroll
    for (int j = 0; j < 16; ++j) {
        int i = base + j * 256 + tid;
        if (i < E) {
            int r = rr[j];
            int b = r >> 7;
            int lp = atomicAdd(&lcur[b], 1);
            int slot = lscan[b] + lp;
            int pk = acol[i] | ((r & 127) << 17);
            ldata[slot] = make_int2(pk, __float_as_int(aval[i]));
            ldest[slot] = ldelta[b] + slot;
        }
    }
    __syncthreads();

    for (int s2 = tid; s2 < cnt; s2 += 256) epk[ldest[s2]] = ldata[s2];
}

// ---- MFMA GEMM body (global A): y_bf16[M x NC] = A[M x 128] @ W[128 x NC] -
template <int NC, bool AF32>
__device__ __forceinline__ void gemm_body(const void* __restrict__ A,
                                          const unsigned short* __restrict__ wT,
                                          unsigned short* __restrict__ y, int M,
                                          int bid, char* smem) {
    constexpr int KP = 136;
    constexpr int NT = NC / 16;
    unsigned short* wl = (unsigned short*)smem;
    const int tid = threadIdx.x;
    for (int idx = tid; idx < NC * 16; idx += 256) {
        int n = idx >> 4, kc = idx & 15;
        *(uint4*)&wl[n * KP + kc * 8] = *(const uint4*)&wT[n * 128 + kc * 8];
    }
    __syncthreads();

    const int wave = tid >> 6;
    const int lane = tid & 63;
    const int m = lane & 15;
    const int q = lane >> 4;
    const int rowbase = bid * 64 + wave * 16;
    const int rowc = min(rowbase + m, M - 1);

    v4f acc[NT] = {};
    union LU { uint4 qv; v8bf b; };

#pragma unroll
    for (int ks = 0; ks < 4; ++ks) {
        const int k0 = ks * 32 + q * 8;
        v8bf a;
        if (AF32) {
            const float* Ap = (const float*)A + (size_t)rowc * 128 + k0;
            float4 f0 = *(const float4*)Ap;
            float4 f1 = *(const float4*)(Ap + 4);
            union { unsigned short s[8]; v8bf b; } cv;
            cv.s[0] = f2bf(f0.x); cv.s[1] = f2bf(f0.y);
            cv.s[2] = f2bf(f0.z); cv.s[3] = f2bf(f0.w);
            cv.s[4] = f2bf(f1.x); cv.s[5] = f2bf(f1.y);
            cv.s[6] = f2bf(f1.z); cv.s[7] = f2bf(f1.w);
            a = cv.b;
        } else {
            LU lu;
            lu.qv = *(const uint4*)((const unsigned short*)A + (size_t)rowc * 128 + k0);
            a = lu.b;
        }
#pragma unroll
        for (int nt = 0; nt < NT; ++nt) {
            v8bf b = *(const v8bf*)&wl[(nt * 16 + m) * KP + k0];
            acc[nt] = __builtin_amdgcn_mfma_f32_16x16x32_bf16(a, b, acc[nt], 0, 0, 0);
        }
    }
#pragma unroll
    for (int nt = 0; nt < NT; ++nt) {
#pragma unroll
        for (int r = 0; r < 4; ++r) {
            int orow = rowbase + q * 4 + r;
            if (orow < M) y[(size_t)orow * NC + nt * 16 + m] = f2bf(acc[nt][r]);
        }
    }
}

// ---- fused: bucket_sort (blocks [0,B)) || gemm1 (blocks [B, B+gb)) --------
__global__ __launch_bounds__(256) void sort_gemm1(const int* __restrict__ boff,
                                                  const int2* __restrict__ epk,
                                                  int2* __restrict__ epkS,
                                                  int* __restrict__ rowptr, int N, int B,
                                                  const float* __restrict__ x,
                                                  const unsigned short* __restrict__ w1T,
                                                  unsigned short* __restrict__ y1b) {
    __shared__ __align__(16) char smem[34816];
    const int tid = threadIdx.x;
    if (blockIdx.x >= B) {
        gemm_body<128, true>(x, w1T, y1b, N, blockIdx.x - B, smem);
        return;
    }
    int2* sorted = (int2*)smem;
    int*  sc     = (int*)(smem + 32768);
    int*  lcur   = (int*)(smem + 32768 + 512);
    const int b = blockIdx.x;
    const int s = boff[b], e = boff[b + 1];
    const int cnt = min(e - s, 4096);
    if (tid < 128) sc[tid] = 0;
    __syncthreads();
    for (int i = s + tid; i < e; i += 256) {
        int rl = (epk[i].x >> 17) & 127;
        atomicAdd(&sc[rl], 1);
    }
    __syncthreads();
    int hv = (tid < 128) ? sc[tid] : 0;
    for (int off = 1; off < 128; off <<= 1) {
        int add = 0;
        if (tid < 128 && tid >= off) add = sc[tid - off];
        __syncthreads();
        if (tid < 128 && tid >= off) sc[tid] += add;
        __syncthreads();
    }
    if (tid < 128) {
        int ex = sc[tid] - hv;
        lcur[tid] = ex;
        int r = b * 128 + tid;
        if (r < N) rowptr[r] = s + ex;
    }
    __syncthreads();
    for (int i = s + tid; i < e; i += 256) {
        int2 p = epk[i];
        int rl = (p.x >> 17) & 127;
        int slot = atomicAdd(&lcur[rl], 1);
        if (slot < 4096) sorted[slot] = make_int2(p.x & 0x1FFFF, p.y);
    }
    __syncthreads();
    for (int i = tid; i < cnt; i += 256) epkS[s + i] = sorted[i];
}

// ---- fused spmm1 + gemm2: block = 64 rows, 2 rows/wave concurrent ---------
// Phase 1: wave w computes h1 rows via dual gather streams (rows base+16w+i
//   and base+16w+i+8, i in 0..8): 16 outstanding gathers/wave. relu(acc+b1)
//   -> bf16 LDS tile (stride 136 shorts).
// Phase 2: y2 tile = h1_tile @ w2 via MFMA; B-frags from L2-resident w2T.
__global__ __launch_bounds__(256) void spmm_gemm2(const int* __restrict__ rowptr,
                                                  const int2* __restrict__ ep,
                                                  const unsigned short* __restrict__ y1b,
                                                  const float* __restrict__ b1,
                                                  const unsigned short* __restrict__ w2T,
                                                  unsigned short* __restrict__ y2b, int N) {
    constexpr int KP = 136;
    __shared__ unsigned short h1[64 * KP];  // 17408 B
    const int tid = threadIdx.x;
    const int wave = tid >> 6, lane = tid & 63;
    const int rowbase = blockIdx.x * 64;
    const unsigned* y32 = (const unsigned*)y1b;
    const float2 bv = ((const float2*)b1)[lane];

    for (int i = 0; i < 8; ++i) {
        const int r0 = rowbase + wave * 16 + i;
        const int r1 = r0 + 8;
        int s0 = 0, e0 = 0, s1 = 0, e1 = 0;
        if (r0 < N) { s0 = rowptr[r0]; e0 = rowptr[r0 + 1]; }
        if (r1 < N) { s1 = rowptr[r1]; e1 = rowptr[r1 + 1]; }
        float a0x = 0.f, a0y = 0.f, a1x = 0.f, a1y = 0.f;
        int2 c0[8], c1[8];
#pragma unroll
        for (int k = 0; k < 8; ++k) { c0[k] = ep[s0 + k]; c1[k] = ep[s1 + k]; }
        int j0 = s0, j1 = s1;
        while (j0 < e0 || j1 < e1) {          // wave-uniform branches
            if (j0 < e0) {
                int2 n0[8];
#pragma unroll
                for (int k = 0; k < 8; ++k) n0[k] = ep[j0 + 8 + k];
#pragma unroll
                for (int k = 0; k < 8; ++k) {
                    float v = (j0 + k < e0) ? __int_as_float(c0[k].y) : 0.f;
                    unsigned u = y32[(size_t)c0[k].x * 64 + lane];
                    a0x += v * __uint_as_float(u << 16);
                    a0y += v * __uint_as_float(u & 0xffff0000u);
                }
#pragma unroll
                for (int k = 0; k < 8; ++k) c0[k] = n0[k];
                j0 += 8;
            }
            if (j1 < e1) {
                int2 n1[8];
#pragma unroll
                for (int k = 0; k < 8; ++k) n1[k] = ep[j1 + 8 + k];
#pragma unroll
                for (int k = 0; k < 8; ++k) {
                    float v = (j1 + k < e1) ? __int_as_float(c1[k].y) : 0.f;
                    unsigned u = y32[(size_t)c1[k].x * 64 + lane];
                    a1x += v * __uint_as_float(u << 16);
                    a1y += v * __uint_as_float(u & 0xffff0000u);
                }
#pragma unroll
                for (int k = 0; k < 8; ++k) c1[k] = n1[k];
                j1 += 8;
            }
        }
        a0x = fmaxf(a0x + bv.x, 0.f);
        a0y = fmaxf(a0y + bv.y, 0.f);
        a1x = fmaxf(a1x + bv.x, 0.f);
        a1y = fmaxf(a1y + bv.y, 0.f);
        *(unsigned*)&h1[(wave * 16 + i) * KP + 2 * lane] =
            ((unsigned)f2bf(a0y) << 16) | f2bf(a0x);
        *(unsigned*)&h1[(wave * 16 + i + 8) * KP + 2 * lane] =
            ((unsigned)f2bf(a1y) << 16) | f2bf(a1x);
    }
    __syncthreads();

    // ---- phase 2: MFMA ----
    const int m = lane & 15, q = lane >> 4;
    v4f acc[4] = {};
#pragma unroll
    for (int ks = 0; ks < 4; ++ks) {
        const int k0 = ks * 32 + q * 8;
        v8bf a = *(const v8bf*)&h1[(wave * 16 + m) * KP + k0];
#pragma unroll
        for (int nt = 0; nt < 4; ++nt) {
            v8bf b = *(const v8bf*)&w2T[(nt * 16 + m) * 128 + k0];
            acc[nt] = __builtin_amdgcn_mfma_f32_16x16x32_bf16(a, b, acc[nt], 0, 0, 0);
        }
    }
#pragma unroll
    for (int nt = 0; nt < 4; ++nt) {
#pragma unroll
        for (int r = 0; r < 4; ++r) {
            int orow = rowbase + wave * 16 + q * 4 + r;
            if (orow < N) y2b[(size_t)orow * 64 + nt * 16 + m] = f2bf(acc[nt][r]);
        }
    }
}

// ---- SPMM CH=64: 2 rows/wave, dual 8-deep gather streams ------------------
__global__ __launch_bounds__(256) void spmm64(const int* __restrict__ rowptr,
                                              const int2* __restrict__ ep,
                                              const unsigned short* __restrict__ yb,
                                              const float* __restrict__ bias,
                                              float* __restrict__ outp, int N) {
    const int gw = (blockIdx.x * 256 + threadIdx.x) >> 6;
    const int lane = threadIdx.x & 63;
    const int r0 = gw * 2, r1 = gw * 2 + 1;
    if (r0 >= N) return;
    int s0 = rowptr[r0], e0 = rowptr[r0 + 1];
    int s1 = 0, e1 = 0;
    if (r1 < N) { s1 = rowptr[r1]; e1 = rowptr[r1 + 1]; }
    float a0 = 0.f, a1 = 0.f;
    int2 c0[8], c1[8];
#pragma unroll
    for (int k = 0; k < 8; ++k) { c0[k] = ep[s0 + k]; c1[k] = ep[s1 + k]; }
    int j0 = s0, j1 = s1;
    while (j0 < e0 || j1 < e1) {              // wave-uniform branches
        if (j0 < e0) {
            int2 n0[8];
#pragma unroll
            for (int k = 0; k < 8; ++k) n0[k] = ep[j0 + 8 + k];
#pragma unroll
            for (int k = 0; k < 8; ++k) {
                float v = (j0 + k < e0) ? __int_as_float(c0[k].y) : 0.f;
                unsigned u = yb[(size_t)c0[k].x * 64 + lane];
                a0 += v * __uint_as_float(u << 16);
            }
#pragma unroll
            for (int k = 0; k < 8; ++k) c0[k] = n0[k];
            j0 += 8;
        }
        if (j1 < e1) {
            int2 n1[8];
#pragma unroll
            for (int k = 0; k < 8; ++k) n1[k] = ep[j1 + 8 + k];
#pragma unroll
            for (int k = 0; k < 8; ++k) {
                float v = (j1 + k < e1) ? __int_as_float(c1[k].y) : 0.f;
                unsigned u = yb[(size_t)c1[k].x * 64 + lane];
                a1 += v * __uint_as_float(u << 16);
            }
#pragma unroll
            for (int k = 0; k < 8; ++k) c1[k] = n1[k];
            j1 += 8;
        }
    }
    const float bl = bias[lane];
    outp[(size_t)r0 * 64 + lane] = a0 + bl;
    if (r1 < N) outp[(size_t)r1 * 64 + lane] = a1 + bl;
}

// ---------------------------------------------------------------------------
extern "C" void kernel_launch(void* const* d_in, const int* in_sizes, int n_in,
                              void* d_out, int out_size, void* d_ws, size_t ws_size,
                              hipStream_t stream) {
    const float* x    = (const float*)d_in[0];
    const int*   arow = (const int*)d_in[1];
    const int*   acol = (const int*)d_in[2];
    const float* aval = (const float*)d_in[3];
    const float* w1   = (const float*)d_in[4];
    const float* b1   = (const float*)d_in[5];
    const float* w2   = (const float*)d_in[6];
    const float* b2   = (const float*)d_in[7];
    float*       out  = (float*)d_out;

    const int N = in_sizes[0] / 128;   // 100000
    const int E = in_sizes[1];         // 1600000
    const int B = (N + 127) >> 7;      // 782 buckets of 128 rows

    char* p = (char*)d_ws;
    auto alloc = [&](size_t bytes) {
        char* r = p;
        p += (bytes + 255) & ~(size_t)255;
        return r;
    };
    int*            counts  = (int*)alloc((size_t)MAXB * 4);
    int*            boff    = (int*)alloc((size_t)(MAXB + 1) * 4);
    int*            gcursor = (int*)alloc((size_t)MAXB * 4);
    int*            rowptr  = (int*)alloc((size_t)(N + 1) * 4);
    int2*           epkS    = (int2*)alloc((size_t)(E + 32) * 8);
    unsigned short* w1T     = (unsigned short*)alloc(128 * 128 * 2);
    unsigned short* w2T     = (unsigned short*)alloc(64 * 128 * 2);
    unsigned short* y1b     = (unsigned short*)alloc((size_t)N * 128 * 2);
    int2*           epk     = (int2*)alloc((size_t)E * 8);
    unsigned short* y2b     = (unsigned short*)alloc((size_t)N * 64 * 2);

    const int gemm_blocks = (N + 63) / 64;   // 1563
    const int pb = (E + 4095) / 4096;        // 391

    hipMemsetAsync(counts, 0, (size_t)MAXB * 4, stream);
    hist_prep<<<pb, 256, 0, stream>>>(arow, counts, E, B, w1, w2, w1T, w2T,
                                      rowptr, epkS, N);
    scan_s<<<1, 256, 0, stream>>>(counts, boff, gcursor, B, E);
    partition_k<<<pb, 256, 0, stream>>>(arow, acol, aval, gcursor, epk, E, B);
    sort_gemm1<<<B + gemm_blocks, 256, 0, stream>>>(boff, epk, epkS, rowptr, N, B,
                                                    x, w1T, y1b);
    spmm_gemm2<<<gemm_blocks, 256, 0, stream>>>(rowptr, epkS, y1b, b1, w2T, y2b, N);
    const int spmm_blocks = (N + 7) / 8;     // 2 rows/wave, 4 waves/block
    spmm64<<<spmm_blocks, 256, 0, stream>>>(rowptr, epkS, y2b, b2, out, N);
}